// Round 13
// baseline (846.264 us; speedup 1.0000x reference)
//
#include <hip/hip_runtime.h>

#define N_NODES 50000
#define N_EDGES 1600000
#define D 128
#define NCHUNK 196            // ceil(N_NODES/256) for scans
#define NBL 16384             // nodes per hist/fill block (64KB LDS)
#define NODEBLKS 4            // ceil(N_NODES/NBL)
#define NPAD 65536            // NODEBLKS*NBL
#define NSEG 128
#define CHUNKS_PER_SEG 3125   // uint4 chunks per segment (E/4/NSEG)
#define SSTR ((size_t)N_NODES*16)   // slab stride in ushorts (16 cols per slab, 8 slabs)
#define SNB 391               // spmm nodeblocks (391*128 = 50048)

typedef _Float16 f16x8 __attribute__((ext_vector_type(8)));
typedef float f32x4 __attribute__((ext_vector_type(4)));
typedef uint u32x4 __attribute__((ext_vector_type(4)));   // ext-vector: valid for nontemporal builtins

union HU { uint4 u; u32x4 v; _Float16 h[8]; };

// ---------------- preprocessing: node-range-owning scan (NO global atomics) ----------------

__global__ __launch_bounds__(1024) void histA_kernel(const int* __restrict__ col, ushort* __restrict__ C){
  __shared__ uint cnt[NBL];
  const int nb = blockIdx.x, s = blockIdx.y;
  const uint n0 = nb*NBL;
  const int t = threadIdx.x;
  #pragma unroll
  for (int k=0;k<NBL/1024;k++) cnt[k*1024 + t] = 0;
  __syncthreads();
  const uint4* cv = (const uint4*)col;
  const int cb = s*CHUNKS_PER_SEG, ce = cb + CHUNKS_PER_SEG;
  for (int c = cb + t; c < ce; c += 1024){
    uint4 v = cv[c];
    unsigned d0 = v.x - n0, d1 = v.y - n0, d2 = v.z - n0, d3 = v.w - n0;
    if (d0 < NBL) atomicAdd(&cnt[d0], 1u);
    if (d1 < NBL) atomicAdd(&cnt[d1], 1u);
    if (d2 < NBL) atomicAdd(&cnt[d2], 1u);
    if (d3 < NBL) atomicAdd(&cnt[d3], 1u);
  }
  __syncthreads();
  #pragma unroll
  for (int k=0;k<NBL/1024;k++)
    C[(size_t)s*NPAD + n0 + k*1024 + t] = (ushort)cnt[k*1024 + t];
}

// In-place exclusive prefix of C along segments; deg, dinv, rdeg=sqrt(deg); fused chunk sums.
__global__ __launch_bounds__(256) void segprefix_kernel(ushort* __restrict__ C, int* __restrict__ deg,
                                                        float* __restrict__ dinv, float* __restrict__ rdeg,
                                                        int* __restrict__ chunkSum){
  __shared__ int red[256];
  int t = threadIdx.x;
  int n = blockIdx.x*256 + t;
  uint run = 0;
  if (n < N_NODES){
    #pragma unroll
    for (int s=0;s<NSEG;s++){
      uint v = C[(size_t)s*NPAD + n];
      C[(size_t)s*NPAD + n] = (ushort)run;
      run += v;
    }
    deg[n] = (int)run;
    dinv[n] = (run > 0) ? rsqrtf((float)run) : 0.0f;
    rdeg[n] = sqrtf((float)run);
  }
  red[t] = (int)run;
  __syncthreads();
  for (int d=128; d>0; d>>=1){
    if (t < d) red[t] += red[t+d];
    __syncthreads();
  }
  if (t == 0) chunkSum[blockIdx.x] = red[0];
}

// off-scan with the chunk-level scan folded in.
__global__ __launch_bounds__(256) void scan3_kernel(const int* __restrict__ deg, const int* __restrict__ chunkSum,
                                                    int* __restrict__ off){
  __shared__ int part[256];
  __shared__ int cbase[256];
  int t = threadIdx.x;
  int cv = (t < NCHUNK) ? chunkSum[t] : 0;
  cbase[t] = cv;
  __syncthreads();
  for (int d=1; d<256; d<<=1){
    int x = (t>=d) ? cbase[t-d] : 0;
    __syncthreads();
    cbase[t] += x;
    __syncthreads();
  }
  int base = (blockIdx.x > 0) ? cbase[blockIdx.x-1] : 0;
  if (blockIdx.x == 0 && t == 0) off[N_NODES] = cbase[NCHUNK-1];
  int i = blockIdx.x*256 + t;
  int v = (i < N_NODES) ? deg[i] : 0;
  part[t] = v;
  __syncthreads();
  for (int d=1; d<256; d<<=1){
    int x = (t>=d) ? part[t-d] : 0;
    __syncthreads();
    part[t] += x;
    __syncthreads();
  }
  if (i < N_NODES) off[i] = base + part[t] - v;
}

// ---------------- CSR fill: LDS cursors, exact per-(block,segment) bases, no global atomics ----------------

__global__ __launch_bounds__(1024) void fillB_kernel(const int* __restrict__ row, const int* __restrict__ col,
                                                     const int* __restrict__ off, const ushort* __restrict__ C,
                                                     ushort* __restrict__ csrS){
  __shared__ uint cur[NBL];
  const int nb = blockIdx.x, s = blockIdx.y;
  const uint n0 = nb*NBL;
  const int t = threadIdx.x;
  #pragma unroll
  for (int k=0;k<NBL/1024;k++){
    int idx = k*1024 + t;
    int n = (int)n0 + idx;
    cur[idx] = (n < N_NODES) ? (uint)off[n] + C[(size_t)s*NPAD + n] : 0u;
  }
  __syncthreads();
  const uint4* cvv = (const uint4*)col;
  const uint4* rvv = (const uint4*)row;
  const int cb = s*CHUNKS_PER_SEG, ce = cb + CHUNKS_PER_SEG;
  for (int c = cb + t; c < ce; c += 1024){
    uint4 cv4 = cvv[c];
    uint4 rv4 = rvv[c];
    unsigned d0 = cv4.x - n0, d1 = cv4.y - n0, d2 = cv4.z - n0, d3 = cv4.w - n0;
    if (d0 < NBL){ uint p = atomicAdd(&cur[d0], 1u); csrS[p] = (ushort)rv4.x; }
    if (d1 < NBL){ uint p = atomicAdd(&cur[d1], 1u); csrS[p] = (ushort)rv4.y; }
    if (d2 < NBL){ uint p = atomicAdd(&cur[d2], 1u); csrS[p] = (ushort)rv4.z; }
    if (d3 < NBL){ uint p = atomicAdd(&cur[d3], 1u); csrS[p] = (ushort)rv4.w; }
  }
}

// ---------------- fp32 -> f16 conversions ----------------
// x16 row-major (gemm s0 input). xs16 SLAB-MAJOR: col c of node n at (c>>4)*SSTR + n*16 + (c&15).

__global__ __launch_bounds__(256) void cvt_x_kernel(const float* __restrict__ x, const float* __restrict__ dinv,
                                                    ushort* __restrict__ x16, ushort* __restrict__ xs16){
  int i = blockIdx.x*256 + threadIdx.x;   // 800000 chunks of 8 f16
  int node = i >> 4, cc = i & 15;
  float di = dinv[node];
  const float4* xin = (const float4*)x;
  float4 a = xin[(size_t)i*2], b = xin[(size_t)i*2+1];
  HU o, os;
  o.h[0]=(_Float16)a.x; o.h[1]=(_Float16)a.y; o.h[2]=(_Float16)a.z; o.h[3]=(_Float16)a.w;
  o.h[4]=(_Float16)b.x; o.h[5]=(_Float16)b.y; o.h[6]=(_Float16)b.z; o.h[7]=(_Float16)b.w;
  os.h[0]=(_Float16)(di*a.x); os.h[1]=(_Float16)(di*a.y); os.h[2]=(_Float16)(di*a.z); os.h[3]=(_Float16)(di*a.w);
  os.h[4]=(_Float16)(di*b.x); os.h[5]=(_Float16)(di*b.y); os.h[6]=(_Float16)(di*b.z); os.h[7]=(_Float16)(di*b.w);
  ((uint4*)x16)[i] = o.u;
  *(uint4*)(xs16 + (size_t)(cc>>1)*SSTR + (size_t)node*16 + (cc&1)*8) = os.u;
}

__global__ __launch_bounds__(256) void cvt_w_kernel(const float* __restrict__ W1, const float* __restrict__ W2,
                                                    const float* __restrict__ W3, const float* __restrict__ Wf,
                                                    ushort* __restrict__ Wt){
  int m = blockIdx.x >> 2, q = blockIdx.x & 3;
  const float* src = (m < 4) ? (W1 + (size_t)m*16384)
                   : (m < 8) ? (W2 + (size_t)(m-4)*16384)
                   : (m < 12)? (W3 + (size_t)(m-8)*16384)
                   : Wf;
  ushort* dst = Wt + (size_t)m*16384;
  for (int it = threadIdx.x; it < 1024; it += 256){
    int idx = q*1024 + it;
    int n  = idx >> 5;
    int k4 = (idx & 31)*4;
    float v0 = src[(size_t)(k4+0)*D + n];
    float v1 = src[(size_t)(k4+1)*D + n];
    float v2 = src[(size_t)(k4+2)*D + n];
    float v3 = src[(size_t)(k4+3)*D + n];
    union { uint2 u; _Float16 h[4]; } o;
    o.h[0]=(_Float16)v0; o.h[1]=(_Float16)v1; o.h[2]=(_Float16)v2; o.h[3]=(_Float16)v3;
    *(uint2*)(dst + (size_t)n*D + k4) = o.u;
  }
}

// ---------------- SpMM: XCD-pinned slab gather ----------------
// slice = blockIdx.x % 8 -> under round-robin dispatch all blocks of slice s land on XCD s;
// that XCD's random working set = one 1.6MB slab (L2-resident) + streamed csr.
// 2 lanes/node (16B each of the 32B slice-row); unroll 16; s-form out, NT store.

__global__ __launch_bounds__(256) void spmm_slab_kernel(const ushort* __restrict__ sIn, ushort* __restrict__ sOut,
                                                        const int* __restrict__ off, const ushort* __restrict__ csrS,
                                                        const float* __restrict__ dinv){
  const int slice = blockIdx.x & 7;
  const int nb = blockIdx.x >> 3;
  const int t = threadIdx.x;
  const int node = nb*128 + (t >> 1);
  if (node >= N_NODES) return;
  const int half8 = (t & 1)*8;
  const ushort* slab = sIn + (size_t)slice*SSTR;
  const int b = off[node], e = off[node+1];
  float acc[8];
  #pragma unroll
  for (int k=0;k<8;k++) acc[k] = 0.f;
  int i = b;
  for (; i+16 <= e; i += 16){
    HU v[16];
    #pragma unroll
    for (int u=0;u<16;u++){
      int s = csrS[i+u];
      v[u].u = *(const uint4*)(slab + (size_t)s*16 + half8);
    }
    #pragma unroll
    for (int u=0;u<16;u++){
      #pragma unroll
      for (int k=0;k<8;k++) acc[k] += (float)v[u].h[k];
    }
  }
  for (; i+4 <= e; i += 4){
    HU v[4];
    #pragma unroll
    for (int u=0;u<4;u++){
      int s = csrS[i+u];
      v[u].u = *(const uint4*)(slab + (size_t)s*16 + half8);
    }
    #pragma unroll
    for (int u=0;u<4;u++){
      #pragma unroll
      for (int k=0;k<8;k++) acc[k] += (float)v[u].h[k];
    }
  }
  for (; i < e; i++){
    int s = csrS[i];
    HU v0; v0.u = *(const uint4*)(slab + (size_t)s*16 + half8);
    #pragma unroll
    for (int k=0;k<8;k++) acc[k] += (float)v0.h[k];
  }
  float di = dinv[node];
  float d2 = di*di;
  HU os;
  #pragma unroll
  for (int k=0;k<8;k++) os.h[k] = (_Float16)(d2*acc[k]);
  __builtin_nontemporal_store(os.v, (u32x4*)(sOut + (size_t)slice*SSTR + (size_t)node*16 + half8));
}

// ---------------- fused layer GEMM via MFMA f16 (r10 structure + coalesced epilogue) ----------------
// out = relu( h0 @ W0 + sum_{k=1..3} (s_k*sqrt(deg)) @ W_k + b ).
// s0 row-major (h-form); s1..s3 slab-major (s-form). HEAD=false: LDS-transpose epilogue -> coalesced
// Ah (row-major 16B) + As (slab-major 16B). HEAD=true: h-tile -> LDS -> head GEMM vs WtH, fp32 out.
// NOTE: out may alias s0 — block reads exactly the rows it writes (staged in src=0), stores after.

template<bool HEAD>
__global__ __launch_bounds__(256) void gemm_mfma_kernel(const ushort* s0,
    const ushort* __restrict__ s1, const ushort* __restrict__ s2, const ushort* __restrict__ s3,
    const ushort* __restrict__ Wt, const float* __restrict__ bias,
    const ushort* __restrict__ WtH, const float* __restrict__ biasH,
    const float* __restrict__ rdeg, const float* __restrict__ dinv,
    ushort* __restrict__ Ah, ushort* __restrict__ As, float* __restrict__ outF){
  __shared__ ushort Xs[64*136];
  const int tid  = threadIdx.x;
  const int wave = tid >> 6, lane = tid & 63;
  const int quad = lane >> 4, l16 = lane & 15;
  const int wm = wave & 1, wn = wave >> 1;
  const int row0 = blockIdx.x * 64;

  f32x4 acc[2][4];
  #pragma unroll
  for (int i=0;i<2;i++)
    #pragma unroll
    for (int j=0;j<4;j++) acc[i][j] = (f32x4){0.f,0.f,0.f,0.f};

  #pragma unroll
  for (int src=0; src<4; src++){
    const ushort* sp = (src==0)?s0:(src==1)?s1:(src==2)?s2:s3;
    __syncthreads();
    for (int i=tid; i<1024; i+=256){
      int r = i >> 4, cc = i & 15;
      int gr = row0 + r;
      HU v; v.u = make_uint4(0u,0u,0u,0u);
      if (gr < N_NODES){
        if (src == 0){
          v.u = *(const uint4*)(sp + (size_t)gr*D + cc*8);
        } else {
          v.u = *(const uint4*)(sp + (size_t)(cc>>1)*SSTR + (size_t)gr*16 + (cc&1)*8);
          float rd = rdeg[gr];
          #pragma unroll
          for (int k=0;k<8;k++) v.h[k] = (_Float16)((float)v.h[k]*rd);
        }
      }
      *(uint4*)(&Xs[r*136 + cc*8]) = v.u;
    }
    __syncthreads();
    const ushort* wsrc = Wt + (size_t)src*16384;
    #pragma unroll
    for (int ks=0; ks<4; ks++){
      f16x8 a0 = *(const f16x8*)(&Xs[(wm*32 +      l16)*136 + ks*32 + quad*8]);
      f16x8 a1 = *(const f16x8*)(&Xs[(wm*32 + 16 + l16)*136 + ks*32 + quad*8]);
      #pragma unroll
      for (int j=0;j<4;j++){
        f16x8 bfrag = *(const f16x8*)(wsrc + (size_t)(wn*64 + j*16 + l16)*D + ks*32 + quad*8);
        acc[0][j] = __builtin_amdgcn_mfma_f32_16x16x32_f16(a0, bfrag, acc[0][j], 0, 0, 0);
        acc[1][j] = __builtin_amdgcn_mfma_f32_16x16x32_f16(a1, bfrag, acc[1][j], 0, 0, 0);
      }
    }
  }

  // h-tile (bias+relu, f16) -> LDS (both paths)
  __syncthreads();
  #pragma unroll
  for (int j=0;j<4;j++){
    int colj = wn*64 + j*16 + l16;
    float bv = bias[colj];
    #pragma unroll
    for (int i=0;i<2;i++){
      int lrow = wm*32 + i*16 + quad*4;
      #pragma unroll
      for (int r=0;r<4;r++){
        float v = fmaxf(acc[i][j][r] + bv, 0.f);
        Xs[(lrow + r)*136 + colj] = __builtin_bit_cast(ushort, (_Float16)v);
      }
    }
  }
  __syncthreads();

  if (!HEAD){
    // coalesced writeback: thread (rbase,cc) stores 16B chunks; Ah row-major, As slab-major.
    const int rbase = tid >> 4, cc = tid & 15;
    #pragma unroll
    for (int p=0;p<4;p++){
      int r = rbase + 16*p, gr = row0 + r;
      if (gr < N_NODES){
        HU h; h.u = *(const uint4*)(&Xs[r*136 + cc*8]);
        *(uint4*)(Ah + (size_t)gr*D + cc*8) = h.u;
        float di = dinv[gr];
        HU s;
        #pragma unroll
        for (int k=0;k<8;k++) s.h[k] = (_Float16)((float)h.h[k]*di);
        *(uint4*)(As + (size_t)(cc>>1)*SSTR + (size_t)gr*16 + (cc&1)*8) = s.u;
      }
    }
  } else {
    // head GEMM vs WtH from the LDS h-tile, fp32 out (coalesced)
    f32x4 acc2[2][4];
    #pragma unroll
    for (int i=0;i<2;i++)
      #pragma unroll
      for (int j=0;j<4;j++) acc2[i][j] = (f32x4){0.f,0.f,0.f,0.f};
    #pragma unroll
    for (int ks=0; ks<4; ks++){
      f16x8 a0 = *(const f16x8*)(&Xs[(wm*32 +      l16)*136 + ks*32 + quad*8]);
      f16x8 a1 = *(const f16x8*)(&Xs[(wm*32 + 16 + l16)*136 + ks*32 + quad*8]);
      #pragma unroll
      for (int j=0;j<4;j++){
        f16x8 bfrag = *(const f16x8*)(WtH + (size_t)(wn*64 + j*16 + l16)*D + ks*32 + quad*8);
        acc2[0][j] = __builtin_amdgcn_mfma_f32_16x16x32_f16(a0, bfrag, acc2[0][j], 0, 0, 0);
        acc2[1][j] = __builtin_amdgcn_mfma_f32_16x16x32_f16(a1, bfrag, acc2[1][j], 0, 0, 0);
      }
    }
    #pragma unroll
    for (int j=0;j<4;j++){
      int colj = wn*64 + j*16 + l16;
      float bv = biasH[colj];
      #pragma unroll
      for (int i=0;i<2;i++){
        int brow = row0 + wm*32 + i*16 + quad*4;
        #pragma unroll
        for (int r=0;r<4;r++){
          int grow = brow + r;
          if (grow < N_NODES)
            outF[(size_t)grow*D + colj] = acc2[i][j][r] + bv;
        }
      }
    }
  }
}

// ---------------- launch ----------------

extern "C" void kernel_launch(void* const* d_in, const int* in_sizes, int n_in,
                              void* d_out, int out_size, void* d_ws, size_t ws_size,
                              hipStream_t stream){
  const float* x  = (const float*)d_in[0];
  const int*   ei = (const int*)d_in[1];
  const float* W1 = (const float*)d_in[2];
  const float* b1 = (const float*)d_in[3];
  const float* W2 = (const float*)d_in[4];
  const float* b2 = (const float*)d_in[5];
  const float* W3 = (const float*)d_in[6];
  const float* b3 = (const float*)d_in[7];
  const float* Wf = (const float*)d_in[8];
  const float* bf = (const float*)d_in[9];
  float* out = (float*)d_out;

  const int* row = ei;            // edge_index[0]
  const int* col = ei + N_EDGES;  // edge_index[1]

  // workspace layout (~82 MB)
  char* w = (char*)d_ws;
  ushort* csrS = (ushort*)w;  w += (size_t)N_EDGES*2;
  ushort* x16  = (ushort*)w;  w += (size_t)N_NODES*D*2;
  ushort* xs16 = (ushort*)w;  w += (size_t)N_NODES*D*2;    // slab-major; reused as Ds after hop-1 (dead then)
  ushort* Ah   = (ushort*)w;  w += (size_t)N_NODES*D*2;    // row-major
  ushort* As   = (ushort*)w;  w += (size_t)N_NODES*D*2;    // slab-major
  ushort* Bs   = (ushort*)w;  w += (size_t)N_NODES*D*2;    // slab-major
  ushort* Cs   = (ushort*)w;  w += (size_t)N_NODES*D*2;    // slab-major
  ushort* Wt   = (ushort*)w;  w += (size_t)13*D*D*2;
  int* deg     = (int*)w;     w += (size_t)N_NODES*4;
  int* off     = (int*)w;     w += (size_t)(N_NODES+1)*4;
  int* chunkS  = (int*)w;     w += (size_t)256*4;
  float* dinv  = (float*)w;   w += (size_t)N_NODES*4;
  float* rdeg  = (float*)w;
  ushort* Ds = xs16;
  // Cc (16.8 MB = NSEG x NPAD ushort) aliases Ah+As: dead before gemm L1 writes Ah/As.
  ushort* Cc = Ah;

  const int GB  = (N_NODES + 63)/64;   // 782
  const int SBS = SNB*8;               // 3128 (8 XCD-pinned slices x 391 nodeblocks)

  histA_kernel<<<dim3(NODEBLKS,NSEG),1024,0,stream>>>(col, Cc);
  segprefix_kernel<<<NCHUNK,256,0,stream>>>(Cc, deg, dinv, rdeg, chunkS);
  scan3_kernel<<<NCHUNK,256,0,stream>>>(deg, chunkS, off);
  fillB_kernel<<<dim3(NODEBLKS,NSEG),1024,0,stream>>>(row, col, off, Cc, csrS);
  cvt_x_kernel<<<3125,256,0,stream>>>(x, dinv, x16, xs16);
  cvt_w_kernel<<<52,256,0,stream>>>(W1, W2, W3, Wf, Wt);

  // layer 1
  spmm_slab_kernel<<<SBS,256,0,stream>>>(xs16, Bs, off, csrS, dinv);
  spmm_slab_kernel<<<SBS,256,0,stream>>>(Bs,   Cs, off, csrS, dinv);
  spmm_slab_kernel<<<SBS,256,0,stream>>>(Cs,   Ds, off, csrS, dinv);
  gemm_mfma_kernel<false><<<GB,256,0,stream>>>(x16, Bs, Cs, Ds, Wt+0*16384, b1, nullptr, nullptr, rdeg, dinv, Ah, As, nullptr);
  // layer 2 (out aliases s0 = Ah; safe, see kernel comment)
  spmm_slab_kernel<<<SBS,256,0,stream>>>(As, Bs, off, csrS, dinv);
  spmm_slab_kernel<<<SBS,256,0,stream>>>(Bs, Cs, off, csrS, dinv);
  spmm_slab_kernel<<<SBS,256,0,stream>>>(Cs, Ds, off, csrS, dinv);
  gemm_mfma_kernel<false><<<GB,256,0,stream>>>(Ah, Bs, Cs, Ds, Wt+4*16384, b2, nullptr, nullptr, rdeg, dinv, Ah, As, nullptr);
  // layer 3 + fused head (fp32 out)
  spmm_slab_kernel<<<SBS,256,0,stream>>>(As, Bs, off, csrS, dinv);
  spmm_slab_kernel<<<SBS,256,0,stream>>>(Bs, Cs, off, csrS, dinv);
  spmm_slab_kernel<<<SBS,256,0,stream>>>(Cs, Ds, off, csrS, dinv);
  gemm_mfma_kernel<true ><<<GB,256,0,stream>>>(Ah, Bs, Cs, Ds, Wt+8*16384, b3, Wt+12*16384, bf, rdeg, dinv, nullptr, nullptr, out);
}

// Round 14
// 644.571 us; speedup vs baseline: 1.3129x; 1.3129x over previous
//
#include <hip/hip_runtime.h>

#define N_NODES 50000
#define N_EDGES 1600000
#define D 128
#define NCHUNK 196            // ceil(N_NODES/256) for scans
#define NBL 16384             // nodes per hist/fill block (64KB LDS)
#define NODEBLKS 4            // ceil(N_NODES/NBL)
#define NPAD 65536            // NODEBLKS*NBL
#define NSEG 128
#define CHUNKS_PER_SEG 3125   // uint4 chunks per segment (E/4/NSEG)
#define SSTR ((size_t)N_NODES*32)   // slab stride in ushorts (32 cols per slab, 4 slabs)
#define SNB 782               // spmm nodeblocks (782*64 = 50048)

typedef _Float16 f16x8 __attribute__((ext_vector_type(8)));
typedef float f32x4 __attribute__((ext_vector_type(4)));
typedef uint u32x4 __attribute__((ext_vector_type(4)));   // ext-vector: valid for nontemporal builtins

union HU { uint4 u; u32x4 v; _Float16 h[8]; };

// ---------------- preprocessing: node-range-owning scan (NO global atomics) ----------------

__global__ __launch_bounds__(1024) void histA_kernel(const int* __restrict__ col, ushort* __restrict__ C){
  __shared__ uint cnt[NBL];
  const int nb = blockIdx.x, s = blockIdx.y;
  const uint n0 = nb*NBL;
  const int t = threadIdx.x;
  #pragma unroll
  for (int k=0;k<NBL/1024;k++) cnt[k*1024 + t] = 0;
  __syncthreads();
  const uint4* cv = (const uint4*)col;
  const int cb = s*CHUNKS_PER_SEG, ce = cb + CHUNKS_PER_SEG;
  for (int c = cb + t; c < ce; c += 1024){
    uint4 v = cv[c];
    unsigned d0 = v.x - n0, d1 = v.y - n0, d2 = v.z - n0, d3 = v.w - n0;
    if (d0 < NBL) atomicAdd(&cnt[d0], 1u);
    if (d1 < NBL) atomicAdd(&cnt[d1], 1u);
    if (d2 < NBL) atomicAdd(&cnt[d2], 1u);
    if (d3 < NBL) atomicAdd(&cnt[d3], 1u);
  }
  __syncthreads();
  #pragma unroll
  for (int k=0;k<NBL/1024;k++)
    C[(size_t)s*NPAD + n0 + k*1024 + t] = (ushort)cnt[k*1024 + t];
}

// In-place exclusive prefix of C along segments; deg, dinv, rdeg=sqrt(deg); fused chunk sums.
__global__ __launch_bounds__(256) void segprefix_kernel(ushort* __restrict__ C, int* __restrict__ deg,
                                                        float* __restrict__ dinv, float* __restrict__ rdeg,
                                                        int* __restrict__ chunkSum){
  __shared__ int red[256];
  int t = threadIdx.x;
  int n = blockIdx.x*256 + t;
  uint run = 0;
  if (n < N_NODES){
    #pragma unroll
    for (int s=0;s<NSEG;s++){
      uint v = C[(size_t)s*NPAD + n];
      C[(size_t)s*NPAD + n] = (ushort)run;
      run += v;
    }
    deg[n] = (int)run;
    dinv[n] = (run > 0) ? rsqrtf((float)run) : 0.0f;
    rdeg[n] = sqrtf((float)run);
  }
  red[t] = (int)run;
  __syncthreads();
  for (int d=128; d>0; d>>=1){
    if (t < d) red[t] += red[t+d];
    __syncthreads();
  }
  if (t == 0) chunkSum[blockIdx.x] = red[0];
}

// off-scan with the chunk-level scan folded in.
__global__ __launch_bounds__(256) void scan3_kernel(const int* __restrict__ deg, const int* __restrict__ chunkSum,
                                                    int* __restrict__ off){
  __shared__ int part[256];
  __shared__ int cbase[256];
  int t = threadIdx.x;
  int cv = (t < NCHUNK) ? chunkSum[t] : 0;
  cbase[t] = cv;
  __syncthreads();
  for (int d=1; d<256; d<<=1){
    int x = (t>=d) ? cbase[t-d] : 0;
    __syncthreads();
    cbase[t] += x;
    __syncthreads();
  }
  int base = (blockIdx.x > 0) ? cbase[blockIdx.x-1] : 0;
  if (blockIdx.x == 0 && t == 0) off[N_NODES] = cbase[NCHUNK-1];
  int i = blockIdx.x*256 + t;
  int v = (i < N_NODES) ? deg[i] : 0;
  part[t] = v;
  __syncthreads();
  for (int d=1; d<256; d<<=1){
    int x = (t>=d) ? part[t-d] : 0;
    __syncthreads();
    part[t] += x;
    __syncthreads();
  }
  if (i < N_NODES) off[i] = base + part[t] - v;
}

// ---------------- CSR fill: LDS cursors, exact per-(block,segment) bases, no global atomics ----------------

__global__ __launch_bounds__(1024) void fillB_kernel(const int* __restrict__ row, const int* __restrict__ col,
                                                     const int* __restrict__ off, const ushort* __restrict__ C,
                                                     ushort* __restrict__ csrS){
  __shared__ uint cur[NBL];
  const int nb = blockIdx.x, s = blockIdx.y;
  const uint n0 = nb*NBL;
  const int t = threadIdx.x;
  #pragma unroll
  for (int k=0;k<NBL/1024;k++){
    int idx = k*1024 + t;
    int n = (int)n0 + idx;
    cur[idx] = (n < N_NODES) ? (uint)off[n] + C[(size_t)s*NPAD + n] : 0u;
  }
  __syncthreads();
  const uint4* cvv = (const uint4*)col;
  const uint4* rvv = (const uint4*)row;
  const int cb = s*CHUNKS_PER_SEG, ce = cb + CHUNKS_PER_SEG;
  for (int c = cb + t; c < ce; c += 1024){
    uint4 cv4 = cvv[c];
    uint4 rv4 = rvv[c];
    unsigned d0 = cv4.x - n0, d1 = cv4.y - n0, d2 = cv4.z - n0, d3 = cv4.w - n0;
    if (d0 < NBL){ uint p = atomicAdd(&cur[d0], 1u); csrS[p] = (ushort)rv4.x; }
    if (d1 < NBL){ uint p = atomicAdd(&cur[d1], 1u); csrS[p] = (ushort)rv4.y; }
    if (d2 < NBL){ uint p = atomicAdd(&cur[d2], 1u); csrS[p] = (ushort)rv4.z; }
    if (d3 < NBL){ uint p = atomicAdd(&cur[d3], 1u); csrS[p] = (ushort)rv4.w; }
  }
}

// ---------------- fp32 -> f16 conversions ----------------
// x16 row-major (gemm s0 input). xs16 SLAB-MAJOR (32-col): col c of node n at (c>>5)*SSTR + n*32 + (c&31).

__global__ __launch_bounds__(256) void cvt_x_kernel(const float* __restrict__ x, const float* __restrict__ dinv,
                                                    ushort* __restrict__ x16, ushort* __restrict__ xs16){
  int i = blockIdx.x*256 + threadIdx.x;   // 800000 chunks of 8 f16
  int node = i >> 4, cc = i & 15;
  float di = dinv[node];
  const float4* xin = (const float4*)x;
  float4 a = xin[(size_t)i*2], b = xin[(size_t)i*2+1];
  HU o, os;
  o.h[0]=(_Float16)a.x; o.h[1]=(_Float16)a.y; o.h[2]=(_Float16)a.z; o.h[3]=(_Float16)a.w;
  o.h[4]=(_Float16)b.x; o.h[5]=(_Float16)b.y; o.h[6]=(_Float16)b.z; o.h[7]=(_Float16)b.w;
  os.h[0]=(_Float16)(di*a.x); os.h[1]=(_Float16)(di*a.y); os.h[2]=(_Float16)(di*a.z); os.h[3]=(_Float16)(di*a.w);
  os.h[4]=(_Float16)(di*b.x); os.h[5]=(_Float16)(di*b.y); os.h[6]=(_Float16)(di*b.z); os.h[7]=(_Float16)(di*b.w);
  ((uint4*)x16)[i] = o.u;
  *(uint4*)(xs16 + (size_t)(cc>>2)*SSTR + (size_t)node*32 + (cc&3)*8) = os.u;
}

__global__ __launch_bounds__(256) void cvt_w_kernel(const float* __restrict__ W1, const float* __restrict__ W2,
                                                    const float* __restrict__ W3, const float* __restrict__ Wf,
                                                    ushort* __restrict__ Wt){
  int m = blockIdx.x >> 2, q = blockIdx.x & 3;
  const float* src = (m < 4) ? (W1 + (size_t)m*16384)
                   : (m < 8) ? (W2 + (size_t)(m-4)*16384)
                   : (m < 12)? (W3 + (size_t)(m-8)*16384)
                   : Wf;
  ushort* dst = Wt + (size_t)m*16384;
  for (int it = threadIdx.x; it < 1024; it += 256){
    int idx = q*1024 + it;
    int n  = idx >> 5;
    int k4 = (idx & 31)*4;
    float v0 = src[(size_t)(k4+0)*D + n];
    float v1 = src[(size_t)(k4+1)*D + n];
    float v2 = src[(size_t)(k4+2)*D + n];
    float v3 = src[(size_t)(k4+3)*D + n];
    union { uint2 u; _Float16 h[4]; } o;
    o.h[0]=(_Float16)v0; o.h[1]=(_Float16)v1; o.h[2]=(_Float16)v2; o.h[3]=(_Float16)v3;
    *(uint2*)(dst + (size_t)n*D + k4) = o.u;
  }
}

// ---------------- SpMM: XCD-pinned 32-col slab gather ----------------
// slice = blockIdx.x % 4 -> XCD k (blockIdx = k mod 8) sees only slice k%4; its random working set
// = one 3.2MB slab (per-XCD-L2-resident, proven pinning per r13 FETCH 144->20MB). 64B rows = one
// 128B line per gather (1-2x amplification vs r13's 4x). 4 lanes/node, unroll 16.

__global__ __launch_bounds__(256) void spmm_slab_kernel(const ushort* __restrict__ sIn, ushort* __restrict__ sOut,
                                                        const int* __restrict__ off, const ushort* __restrict__ csrS,
                                                        const float* __restrict__ dinv){
  const int slice = blockIdx.x & 3;
  const int nb = blockIdx.x >> 2;
  const int t = threadIdx.x;
  const int node = nb*64 + (t >> 2);
  if (node >= N_NODES) return;
  const int q8 = (t & 3)*8;
  const ushort* slab = sIn + (size_t)slice*SSTR;
  const int b = off[node], e = off[node+1];
  float acc[8];
  #pragma unroll
  for (int k=0;k<8;k++) acc[k] = 0.f;
  int i = b;
  for (; i+16 <= e; i += 16){
    HU v[16];
    #pragma unroll
    for (int u=0;u<16;u++){
      int s = csrS[i+u];
      v[u].u = *(const uint4*)(slab + (size_t)s*32 + q8);
    }
    #pragma unroll
    for (int u=0;u<16;u++){
      #pragma unroll
      for (int k=0;k<8;k++) acc[k] += (float)v[u].h[k];
    }
  }
  for (; i+4 <= e; i += 4){
    HU v[4];
    #pragma unroll
    for (int u=0;u<4;u++){
      int s = csrS[i+u];
      v[u].u = *(const uint4*)(slab + (size_t)s*32 + q8);
    }
    #pragma unroll
    for (int u=0;u<4;u++){
      #pragma unroll
      for (int k=0;k<8;k++) acc[k] += (float)v[u].h[k];
    }
  }
  for (; i < e; i++){
    int s = csrS[i];
    HU v0; v0.u = *(const uint4*)(slab + (size_t)s*32 + q8);
    #pragma unroll
    for (int k=0;k<8;k++) acc[k] += (float)v0.h[k];
  }
  float di = dinv[node];
  float d2 = di*di;
  HU os;
  #pragma unroll
  for (int k=0;k<8;k++) os.h[k] = (_Float16)(d2*acc[k]);
  __builtin_nontemporal_store(os.v, (u32x4*)(sOut + (size_t)slice*SSTR + (size_t)node*32 + q8));
}

// ---------------- fused layer GEMM via MFMA f16 (r13 structure: coalesced LDS epilogue) ----------------
// out = relu( h0 @ W0 + sum_{k=1..3} (s_k*sqrt(deg)) @ W_k + b ).
// s0 row-major (h-form); s1..s3 slab-major 32-col (s-form). HEAD=false: LDS epilogue -> coalesced
// Ah (row-major 16B) + As (slab-major 16B). HEAD=true: h-tile -> LDS -> head GEMM vs WtH, fp32 out.
// NOTE: out may alias s0 — block reads exactly the rows it writes (staged in src=0), stores after.

template<bool HEAD>
__global__ __launch_bounds__(256) void gemm_mfma_kernel(const ushort* s0,
    const ushort* __restrict__ s1, const ushort* __restrict__ s2, const ushort* __restrict__ s3,
    const ushort* __restrict__ Wt, const float* __restrict__ bias,
    const ushort* __restrict__ WtH, const float* __restrict__ biasH,
    const float* __restrict__ rdeg, const float* __restrict__ dinv,
    ushort* __restrict__ Ah, ushort* __restrict__ As, float* __restrict__ outF){
  __shared__ ushort Xs[64*136];
  const int tid  = threadIdx.x;
  const int wave = tid >> 6, lane = tid & 63;
  const int quad = lane >> 4, l16 = lane & 15;
  const int wm = wave & 1, wn = wave >> 1;
  const int row0 = blockIdx.x * 64;

  f32x4 acc[2][4];
  #pragma unroll
  for (int i=0;i<2;i++)
    #pragma unroll
    for (int j=0;j<4;j++) acc[i][j] = (f32x4){0.f,0.f,0.f,0.f};

  #pragma unroll
  for (int src=0; src<4; src++){
    const ushort* sp = (src==0)?s0:(src==1)?s1:(src==2)?s2:s3;
    __syncthreads();
    for (int i=tid; i<1024; i+=256){
      int r = i >> 4, cc = i & 15;
      int gr = row0 + r;
      HU v; v.u = make_uint4(0u,0u,0u,0u);
      if (gr < N_NODES){
        if (src == 0){
          v.u = *(const uint4*)(sp + (size_t)gr*D + cc*8);
        } else {
          v.u = *(const uint4*)(sp + (size_t)(cc>>2)*SSTR + (size_t)gr*32 + (cc&3)*8);
          float rd = rdeg[gr];
          #pragma unroll
          for (int k=0;k<8;k++) v.h[k] = (_Float16)((float)v.h[k]*rd);
        }
      }
      *(uint4*)(&Xs[r*136 + cc*8]) = v.u;
    }
    __syncthreads();
    const ushort* wsrc = Wt + (size_t)src*16384;
    #pragma unroll
    for (int ks=0; ks<4; ks++){
      f16x8 a0 = *(const f16x8*)(&Xs[(wm*32 +      l16)*136 + ks*32 + quad*8]);
      f16x8 a1 = *(const f16x8*)(&Xs[(wm*32 + 16 + l16)*136 + ks*32 + quad*8]);
      #pragma unroll
      for (int j=0;j<4;j++){
        f16x8 bfrag = *(const f16x8*)(wsrc + (size_t)(wn*64 + j*16 + l16)*D + ks*32 + quad*8);
        acc[0][j] = __builtin_amdgcn_mfma_f32_16x16x32_f16(a0, bfrag, acc[0][j], 0, 0, 0);
        acc[1][j] = __builtin_amdgcn_mfma_f32_16x16x32_f16(a1, bfrag, acc[1][j], 0, 0, 0);
      }
    }
  }

  // h-tile (bias+relu, f16) -> LDS (both paths)
  __syncthreads();
  #pragma unroll
  for (int j=0;j<4;j++){
    int colj = wn*64 + j*16 + l16;
    float bv = bias[colj];
    #pragma unroll
    for (int i=0;i<2;i++){
      int lrow = wm*32 + i*16 + quad*4;
      #pragma unroll
      for (int r=0;r<4;r++){
        float v = fmaxf(acc[i][j][r] + bv, 0.f);
        Xs[(lrow + r)*136 + colj] = __builtin_bit_cast(ushort, (_Float16)v);
      }
    }
  }
  __syncthreads();

  if (!HEAD){
    // coalesced writeback: thread (rbase,cc) stores 16B chunks; Ah row-major, As slab-major.
    const int rbase = tid >> 4, cc = tid & 15;
    #pragma unroll
    for (int p=0;p<4;p++){
      int r = rbase + 16*p, gr = row0 + r;
      if (gr < N_NODES){
        HU h; h.u = *(const uint4*)(&Xs[r*136 + cc*8]);
        *(uint4*)(Ah + (size_t)gr*D + cc*8) = h.u;
        float di = dinv[gr];
        HU s;
        #pragma unroll
        for (int k=0;k<8;k++) s.h[k] = (_Float16)((float)h.h[k]*di);
        *(uint4*)(As + (size_t)(cc>>2)*SSTR + (size_t)gr*32 + (cc&3)*8) = s.u;
      }
    }
  } else {
    // head GEMM vs WtH from the LDS h-tile, fp32 out (coalesced)
    f32x4 acc2[2][4];
    #pragma unroll
    for (int i=0;i<2;i++)
      #pragma unroll
      for (int j=0;j<4;j++) acc2[i][j] = (f32x4){0.f,0.f,0.f,0.f};
    #pragma unroll
    for (int ks=0; ks<4; ks++){
      f16x8 a0 = *(const f16x8*)(&Xs[(wm*32 +      l16)*136 + ks*32 + quad*8]);
      f16x8 a1 = *(const f16x8*)(&Xs[(wm*32 + 16 + l16)*136 + ks*32 + quad*8]);
      #pragma unroll
      for (int j=0;j<4;j++){
        f16x8 bfrag = *(const f16x8*)(WtH + (size_t)(wn*64 + j*16 + l16)*D + ks*32 + quad*8);
        acc2[0][j] = __builtin_amdgcn_mfma_f32_16x16x32_f16(a0, bfrag, acc2[0][j], 0, 0, 0);
        acc2[1][j] = __builtin_amdgcn_mfma_f32_16x16x32_f16(a1, bfrag, acc2[1][j], 0, 0, 0);
      }
    }
    #pragma unroll
    for (int j=0;j<4;j++){
      int colj = wn*64 + j*16 + l16;
      float bv = biasH[colj];
      #pragma unroll
      for (int i=0;i<2;i++){
        int brow = row0 + wm*32 + i*16 + quad*4;
        #pragma unroll
        for (int r=0;r<4;r++){
          int grow = brow + r;
          if (grow < N_NODES)
            outF[(size_t)grow*D + colj] = acc2[i][j][r] + bv;
        }
      }
    }
  }
}

// ---------------- launch ----------------

extern "C" void kernel_launch(void* const* d_in, const int* in_sizes, int n_in,
                              void* d_out, int out_size, void* d_ws, size_t ws_size,
                              hipStream_t stream){
  const float* x  = (const float*)d_in[0];
  const int*   ei = (const int*)d_in[1];
  const float* W1 = (const float*)d_in[2];
  const float* b1 = (const float*)d_in[3];
  const float* W2 = (const float*)d_in[4];
  const float* b2 = (const float*)d_in[5];
  const float* W3 = (const float*)d_in[6];
  const float* b3 = (const float*)d_in[7];
  const float* Wf = (const float*)d_in[8];
  const float* bf = (const float*)d_in[9];
  float* out = (float*)d_out;

  const int* row = ei;            // edge_index[0]
  const int* col = ei + N_EDGES;  // edge_index[1]

  // workspace layout (~82 MB)
  char* w = (char*)d_ws;
  ushort* csrS = (ushort*)w;  w += (size_t)N_EDGES*2;
  ushort* x16  = (ushort*)w;  w += (size_t)N_NODES*D*2;
  ushort* xs16 = (ushort*)w;  w += (size_t)N_NODES*D*2;    // slab-major; reused as Ds after hop-1 (dead then)
  ushort* Ah   = (ushort*)w;  w += (size_t)N_NODES*D*2;    // row-major
  ushort* As   = (ushort*)w;  w += (size_t)N_NODES*D*2;    // slab-major
  ushort* Bs   = (ushort*)w;  w += (size_t)N_NODES*D*2;    // slab-major
  ushort* Cs   = (ushort*)w;  w += (size_t)N_NODES*D*2;    // slab-major
  ushort* Wt   = (ushort*)w;  w += (size_t)13*D*D*2;
  int* deg     = (int*)w;     w += (size_t)N_NODES*4;
  int* off     = (int*)w;     w += (size_t)(N_NODES+1)*4;
  int* chunkS  = (int*)w;     w += (size_t)256*4;
  float* dinv  = (float*)w;   w += (size_t)N_NODES*4;
  float* rdeg  = (float*)w;
  ushort* Ds = xs16;
  // Cc (16.8 MB = NSEG x NPAD ushort) aliases Ah+As: dead before gemm L1 writes Ah/As.
  ushort* Cc = Ah;

  const int GB  = (N_NODES + 63)/64;   // 782
  const int SBS = SNB*4;               // 3128 (4 XCD-pinned slices x 782 nodeblocks)

  histA_kernel<<<dim3(NODEBLKS,NSEG),1024,0,stream>>>(col, Cc);
  segprefix_kernel<<<NCHUNK,256,0,stream>>>(Cc, deg, dinv, rdeg, chunkS);
  scan3_kernel<<<NCHUNK,256,0,stream>>>(deg, chunkS, off);
  fillB_kernel<<<dim3(NODEBLKS,NSEG),1024,0,stream>>>(row, col, off, Cc, csrS);
  cvt_x_kernel<<<3125,256,0,stream>>>(x, dinv, x16, xs16);
  cvt_w_kernel<<<52,256,0,stream>>>(W1, W2, W3, Wf, Wt);

  // layer 1
  spmm_slab_kernel<<<SBS,256,0,stream>>>(xs16, Bs, off, csrS, dinv);
  spmm_slab_kernel<<<SBS,256,0,stream>>>(Bs,   Cs, off, csrS, dinv);
  spmm_slab_kernel<<<SBS,256,0,stream>>>(Cs,   Ds, off, csrS, dinv);
  gemm_mfma_kernel<false><<<GB,256,0,stream>>>(x16, Bs, Cs, Ds, Wt+0*16384, b1, nullptr, nullptr, rdeg, dinv, Ah, As, nullptr);
  // layer 2 (out aliases s0 = Ah; safe, see kernel comment)
  spmm_slab_kernel<<<SBS,256,0,stream>>>(As, Bs, off, csrS, dinv);
  spmm_slab_kernel<<<SBS,256,0,stream>>>(Bs, Cs, off, csrS, dinv);
  spmm_slab_kernel<<<SBS,256,0,stream>>>(Cs, Ds, off, csrS, dinv);
  gemm_mfma_kernel<false><<<GB,256,0,stream>>>(Ah, Bs, Cs, Ds, Wt+4*16384, b2, nullptr, nullptr, rdeg, dinv, Ah, As, nullptr);
  // layer 3 + fused head (fp32 out)
  spmm_slab_kernel<<<SBS,256,0,stream>>>(As, Bs, off, csrS, dinv);
  spmm_slab_kernel<<<SBS,256,0,stream>>>(Bs, Cs, off, csrS, dinv);
  spmm_slab_kernel<<<SBS,256,0,stream>>>(Cs, Ds, off, csrS, dinv);
  gemm_mfma_kernel<true ><<<GB,256,0,stream>>>(Ah, Bs, Cs, Ds, Wt+8*16384, b3, Wt+12*16384, bf, rdeg, dinv, nullptr, nullptr, out);
}

// Round 15
// 610.575 us; speedup vs baseline: 1.3860x; 1.0557x over previous
//
#include <hip/hip_runtime.h>

#define N_NODES 50000
#define N_EDGES 1600000
#define D 128
#define NCHUNK 196            // ceil(N_NODES/256) for scans
#define NBL 16384             // nodes per hist/fill block (64KB LDS)
#define NODEBLKS 4            // ceil(N_NODES/NBL)
#define NPAD 65536            // NODEBLKS*NBL
#define NSEG 128
#define CHUNKS_PER_SEG 3125   // uint4 chunks per segment (E/4/NSEG)
#define SSTR ((size_t)N_NODES*32)   // slab stride in ushorts (32 cols per slab, 4 slabs)
#define SNB 782               // spmm nodeblocks (782*64 = 50048)

typedef _Float16 f16x8 __attribute__((ext_vector_type(8)));
typedef float f32x4 __attribute__((ext_vector_type(4)));
typedef uint u32x4 __attribute__((ext_vector_type(4)));   // ext-vector: valid for nontemporal builtins

union HU { uint4 u; u32x4 v; _Float16 h[8]; };

// ---------------- preprocessing: node-range-owning scan (NO global atomics) ----------------

__global__ __launch_bounds__(1024) void histA_kernel(const int* __restrict__ col, ushort* __restrict__ C){
  __shared__ uint cnt[NBL];
  const int nb = blockIdx.x, s = blockIdx.y;
  const uint n0 = nb*NBL;
  const int t = threadIdx.x;
  #pragma unroll
  for (int k=0;k<NBL/1024;k++) cnt[k*1024 + t] = 0;
  __syncthreads();
  const uint4* cv = (const uint4*)col;
  const int cb = s*CHUNKS_PER_SEG, ce = cb + CHUNKS_PER_SEG;
  for (int c = cb + t; c < ce; c += 1024){
    uint4 v = cv[c];
    unsigned d0 = v.x - n0, d1 = v.y - n0, d2 = v.z - n0, d3 = v.w - n0;
    if (d0 < NBL) atomicAdd(&cnt[d0], 1u);
    if (d1 < NBL) atomicAdd(&cnt[d1], 1u);
    if (d2 < NBL) atomicAdd(&cnt[d2], 1u);
    if (d3 < NBL) atomicAdd(&cnt[d3], 1u);
  }
  __syncthreads();
  #pragma unroll
  for (int k=0;k<NBL/1024;k++)
    C[(size_t)s*NPAD + n0 + k*1024 + t] = (ushort)cnt[k*1024 + t];
}

// In-place exclusive prefix of C along segments; deg, dinv, rdeg=sqrt(deg); fused chunk sums.
__global__ __launch_bounds__(256) void segprefix_kernel(ushort* __restrict__ C, int* __restrict__ deg,
                                                        float* __restrict__ dinv, float* __restrict__ rdeg,
                                                        int* __restrict__ chunkSum){
  __shared__ int red[256];
  int t = threadIdx.x;
  int n = blockIdx.x*256 + t;
  uint run = 0;
  if (n < N_NODES){
    #pragma unroll
    for (int s=0;s<NSEG;s++){
      uint v = C[(size_t)s*NPAD + n];
      C[(size_t)s*NPAD + n] = (ushort)run;
      run += v;
    }
    deg[n] = (int)run;
    dinv[n] = (run > 0) ? rsqrtf((float)run) : 0.0f;
    rdeg[n] = sqrtf((float)run);
  }
  red[t] = (int)run;
  __syncthreads();
  for (int d=128; d>0; d>>=1){
    if (t < d) red[t] += red[t+d];
    __syncthreads();
  }
  if (t == 0) chunkSum[blockIdx.x] = red[0];
}

// off-scan with the chunk-level scan folded in.
__global__ __launch_bounds__(256) void scan3_kernel(const int* __restrict__ deg, const int* __restrict__ chunkSum,
                                                    int* __restrict__ off){
  __shared__ int part[256];
  __shared__ int cbase[256];
  int t = threadIdx.x;
  int cv = (t < NCHUNK) ? chunkSum[t] : 0;
  cbase[t] = cv;
  __syncthreads();
  for (int d=1; d<256; d<<=1){
    int x = (t>=d) ? cbase[t-d] : 0;
    __syncthreads();
    cbase[t] += x;
    __syncthreads();
  }
  int base = (blockIdx.x > 0) ? cbase[blockIdx.x-1] : 0;
  if (blockIdx.x == 0 && t == 0) off[N_NODES] = cbase[NCHUNK-1];
  int i = blockIdx.x*256 + t;
  int v = (i < N_NODES) ? deg[i] : 0;
  part[t] = v;
  __syncthreads();
  for (int d=1; d<256; d<<=1){
    int x = (t>=d) ? part[t-d] : 0;
    __syncthreads();
    part[t] += x;
    __syncthreads();
  }
  if (i < N_NODES) off[i] = base + part[t] - v;
}

// ---------------- CSR fill: LDS cursors, exact per-(block,segment) bases, no global atomics ----------------

__global__ __launch_bounds__(1024) void fillB_kernel(const int* __restrict__ row, const int* __restrict__ col,
                                                     const int* __restrict__ off, const ushort* __restrict__ C,
                                                     ushort* __restrict__ csrS){
  __shared__ uint cur[NBL];
  const int nb = blockIdx.x, s = blockIdx.y;
  const uint n0 = nb*NBL;
  const int t = threadIdx.x;
  #pragma unroll
  for (int k=0;k<NBL/1024;k++){
    int idx = k*1024 + t;
    int n = (int)n0 + idx;
    cur[idx] = (n < N_NODES) ? (uint)off[n] + C[(size_t)s*NPAD + n] : 0u;
  }
  __syncthreads();
  const uint4* cvv = (const uint4*)col;
  const uint4* rvv = (const uint4*)row;
  const int cb = s*CHUNKS_PER_SEG, ce = cb + CHUNKS_PER_SEG;
  for (int c = cb + t; c < ce; c += 1024){
    uint4 cv4 = cvv[c];
    uint4 rv4 = rvv[c];
    unsigned d0 = cv4.x - n0, d1 = cv4.y - n0, d2 = cv4.z - n0, d3 = cv4.w - n0;
    if (d0 < NBL){ uint p = atomicAdd(&cur[d0], 1u); csrS[p] = (ushort)rv4.x; }
    if (d1 < NBL){ uint p = atomicAdd(&cur[d1], 1u); csrS[p] = (ushort)rv4.y; }
    if (d2 < NBL){ uint p = atomicAdd(&cur[d2], 1u); csrS[p] = (ushort)rv4.z; }
    if (d3 < NBL){ uint p = atomicAdd(&cur[d3], 1u); csrS[p] = (ushort)rv4.w; }
  }
}

// ---------------- fp32 -> f16 conversions ----------------
// x16 row-major (gemm s0 input). xs16 SLAB-MAJOR (32-col): col c of node n at (c>>5)*SSTR + n*32 + (c&31).

__global__ __launch_bounds__(256) void cvt_x_kernel(const float* __restrict__ x, const float* __restrict__ dinv,
                                                    ushort* __restrict__ x16, ushort* __restrict__ xs16){
  int i = blockIdx.x*256 + threadIdx.x;   // 800000 chunks of 8 f16
  int node = i >> 4, cc = i & 15;
  float di = dinv[node];
  const float4* xin = (const float4*)x;
  float4 a = xin[(size_t)i*2], b = xin[(size_t)i*2+1];
  HU o, os;
  o.h[0]=(_Float16)a.x; o.h[1]=(_Float16)a.y; o.h[2]=(_Float16)a.z; o.h[3]=(_Float16)a.w;
  o.h[4]=(_Float16)b.x; o.h[5]=(_Float16)b.y; o.h[6]=(_Float16)b.z; o.h[7]=(_Float16)b.w;
  os.h[0]=(_Float16)(di*a.x); os.h[1]=(_Float16)(di*a.y); os.h[2]=(_Float16)(di*a.z); os.h[3]=(_Float16)(di*a.w);
  os.h[4]=(_Float16)(di*b.x); os.h[5]=(_Float16)(di*b.y); os.h[6]=(_Float16)(di*b.z); os.h[7]=(_Float16)(di*b.w);
  ((uint4*)x16)[i] = o.u;
  *(uint4*)(xs16 + (size_t)(cc>>2)*SSTR + (size_t)node*32 + (cc&3)*8) = os.u;
}

__global__ __launch_bounds__(256) void cvt_w_kernel(const float* __restrict__ W1, const float* __restrict__ W2,
                                                    const float* __restrict__ W3, const float* __restrict__ Wf,
                                                    ushort* __restrict__ Wt){
  int m = blockIdx.x >> 2, q = blockIdx.x & 3;
  const float* src = (m < 4) ? (W1 + (size_t)m*16384)
                   : (m < 8) ? (W2 + (size_t)(m-4)*16384)
                   : (m < 12)? (W3 + (size_t)(m-8)*16384)
                   : Wf;
  ushort* dst = Wt + (size_t)m*16384;
  for (int it = threadIdx.x; it < 1024; it += 256){
    int idx = q*1024 + it;
    int n  = idx >> 5;
    int k4 = (idx & 31)*4;
    float v0 = src[(size_t)(k4+0)*D + n];
    float v1 = src[(size_t)(k4+1)*D + n];
    float v2 = src[(size_t)(k4+2)*D + n];
    float v3 = src[(size_t)(k4+3)*D + n];
    union { uint2 u; _Float16 h[4]; } o;
    o.h[0]=(_Float16)v0; o.h[1]=(_Float16)v1; o.h[2]=(_Float16)v2; o.h[3]=(_Float16)v3;
    *(uint2*)(dst + (size_t)n*D + k4) = o.u;
  }
}

// ---------------- SpMM: XCD-pinned 32-col slab gather (r14, unchanged) ----------------

__global__ __launch_bounds__(256) void spmm_slab_kernel(const ushort* __restrict__ sIn, ushort* __restrict__ sOut,
                                                        const int* __restrict__ off, const ushort* __restrict__ csrS,
                                                        const float* __restrict__ dinv){
  const int slice = blockIdx.x & 3;
  const int nb = blockIdx.x >> 2;
  const int t = threadIdx.x;
  const int node = nb*64 + (t >> 2);
  if (node >= N_NODES) return;
  const int q8 = (t & 3)*8;
  const ushort* slab = sIn + (size_t)slice*SSTR;
  const int b = off[node], e = off[node+1];
  float acc[8];
  #pragma unroll
  for (int k=0;k<8;k++) acc[k] = 0.f;
  int i = b;
  for (; i+16 <= e; i += 16){
    HU v[16];
    #pragma unroll
    for (int u=0;u<16;u++){
      int s = csrS[i+u];
      v[u].u = *(const uint4*)(slab + (size_t)s*32 + q8);
    }
    #pragma unroll
    for (int u=0;u<16;u++){
      #pragma unroll
      for (int k=0;k<8;k++) acc[k] += (float)v[u].h[k];
    }
  }
  for (; i+4 <= e; i += 4){
    HU v[4];
    #pragma unroll
    for (int u=0;u<4;u++){
      int s = csrS[i+u];
      v[u].u = *(const uint4*)(slab + (size_t)s*32 + q8);
    }
    #pragma unroll
    for (int u=0;u<4;u++){
      #pragma unroll
      for (int k=0;k<8;k++) acc[k] += (float)v[u].h[k];
    }
  }
  for (; i < e; i++){
    int s = csrS[i];
    HU v0; v0.u = *(const uint4*)(slab + (size_t)s*32 + q8);
    #pragma unroll
    for (int k=0;k<8;k++) acc[k] += (float)v0.h[k];
  }
  float di = dinv[node];
  float d2 = di*di;
  HU os;
  #pragma unroll
  for (int k=0;k<8;k++) os.h[k] = (_Float16)(d2*acc[k]);
  __builtin_nontemporal_store(os.v, (u32x4*)(sOut + (size_t)slice*SSTR + (size_t)node*32 + q8));
}

// ---------------- fused layer GEMM via MFMA f16 — weights staged through LDS ----------------
// out = relu( h0 @ W0 + sum_{k=1..3} (s_k*sqrt(deg)) @ W_k + b ).
// Per src: W_src (32KB) staged coalesced into Ws (pad 136) + X tile into Xs; b-frags via ds_read
// (was: 512KB/block scattered global reads -> now 128KB/block coalesced).
// HEAD=false: LDS epilogue -> coalesced Ah (row-major) + As (slab-major).
// HEAD=true: h-tile -> Xs, WtH -> Ws, head GEMM, fp32 out.
// NOTE: out may alias s0 — block reads exactly the rows it writes (staged in src=0), stores after.

template<bool HEAD>
__global__ __launch_bounds__(256) void gemm_mfma_kernel(const ushort* s0,
    const ushort* __restrict__ s1, const ushort* __restrict__ s2, const ushort* __restrict__ s3,
    const ushort* __restrict__ Wt, const float* __restrict__ bias,
    const ushort* __restrict__ WtH, const float* __restrict__ biasH,
    const float* __restrict__ rdeg, const float* __restrict__ dinv,
    ushort* __restrict__ Ah, ushort* __restrict__ As, float* __restrict__ outF){
  __shared__ ushort Xs[64*136];
  __shared__ ushort Ws[128*136];
  const int tid  = threadIdx.x;
  const int wave = tid >> 6, lane = tid & 63;
  const int quad = lane >> 4, l16 = lane & 15;
  const int wm = wave & 1, wn = wave >> 1;
  const int row0 = blockIdx.x * 64;

  f32x4 acc[2][4];
  #pragma unroll
  for (int i=0;i<2;i++)
    #pragma unroll
    for (int j=0;j<4;j++) acc[i][j] = (f32x4){0.f,0.f,0.f,0.f};

  #pragma unroll
  for (int src=0; src<4; src++){
    const ushort* sp = (src==0)?s0:(src==1)?s1:(src==2)?s2:s3;
    const ushort* wsrc = Wt + (size_t)src*16384;
    __syncthreads();
    // stage X tile (64 rows x 128 f16)
    #pragma unroll
    for (int p=0;p<4;p++){
      int i = tid + p*256;
      int r = i >> 4, cc = i & 15;
      int gr = row0 + r;
      HU v; v.u = make_uint4(0u,0u,0u,0u);
      if (gr < N_NODES){
        if (src == 0){
          v.u = *(const uint4*)(sp + (size_t)gr*D + cc*8);
        } else {
          v.u = *(const uint4*)(sp + (size_t)(cc>>2)*SSTR + (size_t)gr*32 + (cc&3)*8);
          float rd = rdeg[gr];
          #pragma unroll
          for (int k=0;k<8;k++) v.h[k] = (_Float16)((float)v.h[k]*rd);
        }
      }
      *(uint4*)(&Xs[r*136 + cc*8]) = v.u;
    }
    // stage W_src (128 rows [n] x 128 f16 [k], coalesced)
    #pragma unroll
    for (int p=0;p<8;p++){
      int i = tid + p*256;
      int n = i >> 4, cc = i & 15;
      *(uint4*)(&Ws[n*136 + cc*8]) = *(const uint4*)(wsrc + (size_t)n*D + cc*8);
    }
    __syncthreads();
    #pragma unroll
    for (int ks=0; ks<4; ks++){
      f16x8 a0 = *(const f16x8*)(&Xs[(wm*32 +      l16)*136 + ks*32 + quad*8]);
      f16x8 a1 = *(const f16x8*)(&Xs[(wm*32 + 16 + l16)*136 + ks*32 + quad*8]);
      #pragma unroll
      for (int j=0;j<4;j++){
        f16x8 bfrag = *(const f16x8*)(&Ws[(wn*64 + j*16 + l16)*136 + ks*32 + quad*8]);
        acc[0][j] = __builtin_amdgcn_mfma_f32_16x16x32_f16(a0, bfrag, acc[0][j], 0, 0, 0);
        acc[1][j] = __builtin_amdgcn_mfma_f32_16x16x32_f16(a1, bfrag, acc[1][j], 0, 0, 0);
      }
    }
  }

  // h-tile (bias+relu, f16) -> Xs (both paths); HEAD also stages WtH -> Ws
  __syncthreads();
  #pragma unroll
  for (int j=0;j<4;j++){
    int colj = wn*64 + j*16 + l16;
    float bv = bias[colj];
    #pragma unroll
    for (int i=0;i<2;i++){
      int lrow = wm*32 + i*16 + quad*4;
      #pragma unroll
      for (int r=0;r<4;r++){
        float v = fmaxf(acc[i][j][r] + bv, 0.f);
        Xs[(lrow + r)*136 + colj] = __builtin_bit_cast(ushort, (_Float16)v);
      }
    }
  }
  if (HEAD){
    #pragma unroll
    for (int p=0;p<8;p++){
      int i = tid + p*256;
      int n = i >> 4, cc = i & 15;
      *(uint4*)(&Ws[n*136 + cc*8]) = *(const uint4*)(WtH + (size_t)n*D + cc*8);
    }
  }
  __syncthreads();

  if (!HEAD){
    // coalesced writeback: thread (rbase,cc) stores 16B chunks; Ah row-major, As slab-major.
    const int rbase = tid >> 4, cc = tid & 15;
    #pragma unroll
    for (int p=0;p<4;p++){
      int r = rbase + 16*p, gr = row0 + r;
      if (gr < N_NODES){
        HU h; h.u = *(const uint4*)(&Xs[r*136 + cc*8]);
        *(uint4*)(Ah + (size_t)gr*D + cc*8) = h.u;
        float di = dinv[gr];
        HU s;
        #pragma unroll
        for (int k=0;k<8;k++) s.h[k] = (_Float16)((float)h.h[k]*di);
        *(uint4*)(As + (size_t)(cc>>2)*SSTR + (size_t)gr*32 + (cc&3)*8) = s.u;
      }
    }
  } else {
    // head GEMM from LDS h-tile vs LDS WtH, fp32 out (coalesced)
    f32x4 acc2[2][4];
    #pragma unroll
    for (int i=0;i<2;i++)
      #pragma unroll
      for (int j=0;j<4;j++) acc2[i][j] = (f32x4){0.f,0.f,0.f,0.f};
    #pragma unroll
    for (int ks=0; ks<4; ks++){
      f16x8 a0 = *(const f16x8*)(&Xs[(wm*32 +      l16)*136 + ks*32 + quad*8]);
      f16x8 a1 = *(const f16x8*)(&Xs[(wm*32 + 16 + l16)*136 + ks*32 + quad*8]);
      #pragma unroll
      for (int j=0;j<4;j++){
        f16x8 bfrag = *(const f16x8*)(&Ws[(wn*64 + j*16 + l16)*136 + ks*32 + quad*8]);
        acc2[0][j] = __builtin_amdgcn_mfma_f32_16x16x32_f16(a0, bfrag, acc2[0][j], 0, 0, 0);
        acc2[1][j] = __builtin_amdgcn_mfma_f32_16x16x32_f16(a1, bfrag, acc2[1][j], 0, 0, 0);
      }
    }
    #pragma unroll
    for (int j=0;j<4;j++){
      int colj = wn*64 + j*16 + l16;
      float bv = biasH[colj];
      #pragma unroll
      for (int i=0;i<2;i++){
        int brow = row0 + wm*32 + i*16 + quad*4;
        #pragma unroll
        for (int r=0;r<4;r++){
          int grow = brow + r;
          if (grow < N_NODES)
            outF[(size_t)grow*D + colj] = acc2[i][j][r] + bv;
        }
      }
    }
  }
}

// ---------------- launch ----------------

extern "C" void kernel_launch(void* const* d_in, const int* in_sizes, int n_in,
                              void* d_out, int out_size, void* d_ws, size_t ws_size,
                              hipStream_t stream){
  const float* x  = (const float*)d_in[0];
  const int*   ei = (const int*)d_in[1];
  const float* W1 = (const float*)d_in[2];
  const float* b1 = (const float*)d_in[3];
  const float* W2 = (const float*)d_in[4];
  const float* b2 = (const float*)d_in[5];
  const float* W3 = (const float*)d_in[6];
  const float* b3 = (const float*)d_in[7];
  const float* Wf = (const float*)d_in[8];
  const float* bf = (const float*)d_in[9];
  float* out = (float*)d_out;

  const int* row = ei;            // edge_index[0]
  const int* col = ei + N_EDGES;  // edge_index[1]

  // workspace layout (~82 MB)
  char* w = (char*)d_ws;
  ushort* csrS = (ushort*)w;  w += (size_t)N_EDGES*2;
  ushort* x16  = (ushort*)w;  w += (size_t)N_NODES*D*2;
  ushort* xs16 = (ushort*)w;  w += (size_t)N_NODES*D*2;    // slab-major; reused as Ds after hop-1 (dead then)
  ushort* Ah   = (ushort*)w;  w += (size_t)N_NODES*D*2;    // row-major
  ushort* As   = (ushort*)w;  w += (size_t)N_NODES*D*2;    // slab-major
  ushort* Bs   = (ushort*)w;  w += (size_t)N_NODES*D*2;    // slab-major
  ushort* Cs   = (ushort*)w;  w += (size_t)N_NODES*D*2;    // slab-major
  ushort* Wt   = (ushort*)w;  w += (size_t)13*D*D*2;
  int* deg     = (int*)w;     w += (size_t)N_NODES*4;
  int* off     = (int*)w;     w += (size_t)(N_NODES+1)*4;
  int* chunkS  = (int*)w;     w += (size_t)256*4;
  float* dinv  = (float*)w;   w += (size_t)N_NODES*4;
  float* rdeg  = (float*)w;
  ushort* Ds = xs16;
  // Cc (16.8 MB = NSEG x NPAD ushort) aliases Ah+As: dead before gemm L1 writes Ah/As.
  ushort* Cc = Ah;

  const int GB  = (N_NODES + 63)/64;   // 782
  const int SBS = SNB*4;               // 3128 (4 XCD-pinned slices x 782 nodeblocks)

  histA_kernel<<<dim3(NODEBLKS,NSEG),1024,0,stream>>>(col, Cc);
  segprefix_kernel<<<NCHUNK,256,0,stream>>>(Cc, deg, dinv, rdeg, chunkS);
  scan3_kernel<<<NCHUNK,256,0,stream>>>(deg, chunkS, off);
  fillB_kernel<<<dim3(NODEBLKS,NSEG),1024,0,stream>>>(row, col, off, Cc, csrS);
  cvt_x_kernel<<<3125,256,0,stream>>>(x, dinv, x16, xs16);
  cvt_w_kernel<<<52,256,0,stream>>>(W1, W2, W3, Wf, Wt);

  // layer 1
  spmm_slab_kernel<<<SBS,256,0,stream>>>(xs16, Bs, off, csrS, dinv);
  spmm_slab_kernel<<<SBS,256,0,stream>>>(Bs,   Cs, off, csrS, dinv);
  spmm_slab_kernel<<<SBS,256,0,stream>>>(Cs,   Ds, off, csrS, dinv);
  gemm_mfma_kernel<false><<<GB,256,0,stream>>>(x16, Bs, Cs, Ds, Wt+0*16384, b1, nullptr, nullptr, rdeg, dinv, Ah, As, nullptr);
  // layer 2 (out aliases s0 = Ah; safe, see kernel comment)
  spmm_slab_kernel<<<SBS,256,0,stream>>>(As, Bs, off, csrS, dinv);
  spmm_slab_kernel<<<SBS,256,0,stream>>>(Bs, Cs, off, csrS, dinv);
  spmm_slab_kernel<<<SBS,256,0,stream>>>(Cs, Ds, off, csrS, dinv);
  gemm_mfma_kernel<false><<<GB,256,0,stream>>>(Ah, Bs, Cs, Ds, Wt+4*16384, b2, nullptr, nullptr, rdeg, dinv, Ah, As, nullptr);
  // layer 3 + fused head (fp32 out)
  spmm_slab_kernel<<<SBS,256,0,stream>>>(As, Bs, off, csrS, dinv);
  spmm_slab_kernel<<<SBS,256,0,stream>>>(Bs, Cs, off, csrS, dinv);
  spmm_slab_kernel<<<SBS,256,0,stream>>>(Cs, Ds, off, csrS, dinv);
  gemm_mfma_kernel<true ><<<GB,256,0,stream>>>(Ah, Bs, Cs, Ds, Wt+8*16384, b3, Wt+12*16384, bf, rdeg, dinv, nullptr, nullptr, out);
}

// Round 16
// 554.204 us; speedup vs baseline: 1.5270x; 1.1017x over previous
//
#include <hip/hip_runtime.h>

#define N_NODES 50000
#define N_EDGES 1600000
#define D 128
#define NCHUNK 196            // ceil(N_NODES/256) for scans
#define NBL 16384             // nodes per hist/fill block (64KB LDS)
#define NODEBLKS 4            // ceil(N_NODES/NBL)
#define NPAD 65536            // NODEBLKS*NBL
#define NSEG 128
#define CHUNKS_PER_SEG 3125   // uint4 chunks per segment (E/4/NSEG)
#define SSTR ((size_t)N_NODES*32)   // slab stride in ushorts (32 cols per slab, 4 slabs)
#define SNB 782               // spmm nodeblocks (782*64 = 50048)
#define CSR_CAP 4608          // staged csr entries per spmm block (mean 2048, sigma ~45 -> 12+ sigma margin)

typedef _Float16 f16x8 __attribute__((ext_vector_type(8)));
typedef float f32x4 __attribute__((ext_vector_type(4)));
typedef uint u32x4 __attribute__((ext_vector_type(4)));   // ext-vector: valid for nontemporal builtins

union HU { uint4 u; u32x4 v; _Float16 h[8]; };

// ---------------- preprocessing: node-range-owning scan (NO global atomics) ----------------

__global__ __launch_bounds__(1024) void histA_kernel(const int* __restrict__ col, ushort* __restrict__ C){
  __shared__ uint cnt[NBL];
  const int nb = blockIdx.x, s = blockIdx.y;
  const uint n0 = nb*NBL;
  const int t = threadIdx.x;
  #pragma unroll
  for (int k=0;k<NBL/1024;k++) cnt[k*1024 + t] = 0;
  __syncthreads();
  const uint4* cv = (const uint4*)col;
  const int cb = s*CHUNKS_PER_SEG, ce = cb + CHUNKS_PER_SEG;
  for (int c = cb + t; c < ce; c += 1024){
    uint4 v = cv[c];
    unsigned d0 = v.x - n0, d1 = v.y - n0, d2 = v.z - n0, d3 = v.w - n0;
    if (d0 < NBL) atomicAdd(&cnt[d0], 1u);
    if (d1 < NBL) atomicAdd(&cnt[d1], 1u);
    if (d2 < NBL) atomicAdd(&cnt[d2], 1u);
    if (d3 < NBL) atomicAdd(&cnt[d3], 1u);
  }
  __syncthreads();
  #pragma unroll
  for (int k=0;k<NBL/1024;k++)
    C[(size_t)s*NPAD + n0 + k*1024 + t] = (ushort)cnt[k*1024 + t];
}

// In-place exclusive prefix of C along segments; deg, dinv, rdeg=sqrt(deg); fused chunk sums.
__global__ __launch_bounds__(256) void segprefix_kernel(ushort* __restrict__ C, int* __restrict__ deg,
                                                        float* __restrict__ dinv, float* __restrict__ rdeg,
                                                        int* __restrict__ chunkSum){
  __shared__ int red[256];
  int t = threadIdx.x;
  int n = blockIdx.x*256 + t;
  uint run = 0;
  if (n < N_NODES){
    #pragma unroll
    for (int s=0;s<NSEG;s++){
      uint v = C[(size_t)s*NPAD + n];
      C[(size_t)s*NPAD + n] = (ushort)run;
      run += v;
    }
    deg[n] = (int)run;
    dinv[n] = (run > 0) ? rsqrtf((float)run) : 0.0f;
    rdeg[n] = sqrtf((float)run);
  }
  red[t] = (int)run;
  __syncthreads();
  for (int d=128; d>0; d>>=1){
    if (t < d) red[t] += red[t+d];
    __syncthreads();
  }
  if (t == 0) chunkSum[blockIdx.x] = red[0];
}

// off-scan with the chunk-level scan folded in.
__global__ __launch_bounds__(256) void scan3_kernel(const int* __restrict__ deg, const int* __restrict__ chunkSum,
                                                    int* __restrict__ off){
  __shared__ int part[256];
  __shared__ int cbase[256];
  int t = threadIdx.x;
  int cv = (t < NCHUNK) ? chunkSum[t] : 0;
  cbase[t] = cv;
  __syncthreads();
  for (int d=1; d<256; d<<=1){
    int x = (t>=d) ? cbase[t-d] : 0;
    __syncthreads();
    cbase[t] += x;
    __syncthreads();
  }
  int base = (blockIdx.x > 0) ? cbase[blockIdx.x-1] : 0;
  if (blockIdx.x == 0 && t == 0) off[N_NODES] = cbase[NCHUNK-1];
  int i = blockIdx.x*256 + t;
  int v = (i < N_NODES) ? deg[i] : 0;
  part[t] = v;
  __syncthreads();
  for (int d=1; d<256; d<<=1){
    int x = (t>=d) ? part[t-d] : 0;
    __syncthreads();
    part[t] += x;
    __syncthreads();
  }
  if (i < N_NODES) off[i] = base + part[t] - v;
}

// ---------------- CSR fill: LDS cursors, exact per-(block,segment) bases, no global atomics ----------------

__global__ __launch_bounds__(1024) void fillB_kernel(const int* __restrict__ row, const int* __restrict__ col,
                                                     const int* __restrict__ off, const ushort* __restrict__ C,
                                                     ushort* __restrict__ csrS){
  __shared__ uint cur[NBL];
  const int nb = blockIdx.x, s = blockIdx.y;
  const uint n0 = nb*NBL;
  const int t = threadIdx.x;
  #pragma unroll
  for (int k=0;k<NBL/1024;k++){
    int idx = k*1024 + t;
    int n = (int)n0 + idx;
    cur[idx] = (n < N_NODES) ? (uint)off[n] + C[(size_t)s*NPAD + n] : 0u;
  }
  __syncthreads();
  const uint4* cvv = (const uint4*)col;
  const uint4* rvv = (const uint4*)row;
  const int cb = s*CHUNKS_PER_SEG, ce = cb + CHUNKS_PER_SEG;
  for (int c = cb + t; c < ce; c += 1024){
    uint4 cv4 = cvv[c];
    uint4 rv4 = rvv[c];
    unsigned d0 = cv4.x - n0, d1 = cv4.y - n0, d2 = cv4.z - n0, d3 = cv4.w - n0;
    if (d0 < NBL){ uint p = atomicAdd(&cur[d0], 1u); csrS[p] = (ushort)rv4.x; }
    if (d1 < NBL){ uint p = atomicAdd(&cur[d1], 1u); csrS[p] = (ushort)rv4.y; }
    if (d2 < NBL){ uint p = atomicAdd(&cur[d2], 1u); csrS[p] = (ushort)rv4.z; }
    if (d3 < NBL){ uint p = atomicAdd(&cur[d3], 1u); csrS[p] = (ushort)rv4.w; }
  }
}

// ---------------- fp32 -> f16 conversions ----------------
// x16 row-major (gemm s0 input). xs16 SLAB-MAJOR (32-col): col c of node n at (c>>5)*SSTR + n*32 + (c&31).

__global__ __launch_bounds__(256) void cvt_x_kernel(const float* __restrict__ x, const float* __restrict__ dinv,
                                                    ushort* __restrict__ x16, ushort* __restrict__ xs16){
  int i = blockIdx.x*256 + threadIdx.x;   // 800000 chunks of 8 f16
  int node = i >> 4, cc = i & 15;
  float di = dinv[node];
  const float4* xin = (const float4*)x;
  float4 a = xin[(size_t)i*2], b = xin[(size_t)i*2+1];
  HU o, os;
  o.h[0]=(_Float16)a.x; o.h[1]=(_Float16)a.y; o.h[2]=(_Float16)a.z; o.h[3]=(_Float16)a.w;
  o.h[4]=(_Float16)b.x; o.h[5]=(_Float16)b.y; o.h[6]=(_Float16)b.z; o.h[7]=(_Float16)b.w;
  os.h[0]=(_Float16)(di*a.x); os.h[1]=(_Float16)(di*a.y); os.h[2]=(_Float16)(di*a.z); os.h[3]=(_Float16)(di*a.w);
  os.h[4]=(_Float16)(di*b.x); os.h[5]=(_Float16)(di*b.y); os.h[6]=(_Float16)(di*b.z); os.h[7]=(_Float16)(di*b.w);
  ((uint4*)x16)[i] = o.u;
  *(uint4*)(xs16 + (size_t)(cc>>2)*SSTR + (size_t)node*32 + (cc&3)*8) = os.u;
}

__global__ __launch_bounds__(256) void cvt_w_kernel(const float* __restrict__ W1, const float* __restrict__ W2,
                                                    const float* __restrict__ W3, const float* __restrict__ Wf,
                                                    ushort* __restrict__ Wt){
  int m = blockIdx.x >> 2, q = blockIdx.x & 3;
  const float* src = (m < 4) ? (W1 + (size_t)m*16384)
                   : (m < 8) ? (W2 + (size_t)(m-4)*16384)
                   : (m < 12)? (W3 + (size_t)(m-8)*16384)
                   : Wf;
  ushort* dst = Wt + (size_t)m*16384;
  for (int it = threadIdx.x; it < 1024; it += 256){
    int idx = q*1024 + it;
    int n  = idx >> 5;
    int k4 = (idx & 31)*4;
    float v0 = src[(size_t)(k4+0)*D + n];
    float v1 = src[(size_t)(k4+1)*D + n];
    float v2 = src[(size_t)(k4+2)*D + n];
    float v3 = src[(size_t)(k4+3)*D + n];
    union { uint2 u; _Float16 h[4]; } o;
    o.h[0]=(_Float16)v0; o.h[1]=(_Float16)v1; o.h[2]=(_Float16)v2; o.h[3]=(_Float16)v3;
    *(uint2*)(dst + (size_t)n*D + k4) = o.u;
  }
}

// ---------------- SpMM: XCD-pinned 32-col slab gather, csr window staged in LDS ----------------
// slice = blockIdx.x % 4 -> XCD-pinned slab (3.2MB, L2-resident; proven r13/r14).
// Block's csr window off[n0]..off[n0+64] is CONTIGUOUS -> staged coalesced into LDS once;
// inner loop reads indices via ds_read (quad-broadcast) instead of 16 scattered 2B global loads
// per chunk — halves VMEM instruction count / TA work. Uniform fallback if window > CSR_CAP.

__global__ __launch_bounds__(256) void spmm_slab_kernel(const ushort* __restrict__ sIn, ushort* __restrict__ sOut,
                                                        const int* __restrict__ off, const ushort* __restrict__ csrS,
                                                        const float* __restrict__ dinv){
  __shared__ alignas(16) ushort csrL[CSR_CAP];
  const int slice = blockIdx.x & 3;
  const int nb = blockIdx.x >> 2;
  const int t = threadIdx.x;
  const int node0 = nb*64;
  const int node = node0 + (t >> 2);
  const int q8 = (t & 3)*8;
  const ushort* slab = sIn + (size_t)slice*SSTR;

  // stage csr window (aligned, coalesced). Tail over-read <=14B lands in adjacent ws buffer: safe.
  const int wb = off[node0];
  int wn = node0 + 64; if (wn > N_NODES) wn = N_NODES;
  const int we = off[wn];
  const int start = wb & ~7;
  const int len = we - start;
  const bool useLds = (len <= CSR_CAP);
  if (useLds){
    const int nch = (len + 7) >> 3;
    for (int j = t; j < nch; j += 256)
      *(uint4*)(&csrL[j*8]) = *(const uint4*)(csrS + (size_t)start + (size_t)j*8);
  }
  __syncthreads();

  if (node >= N_NODES) return;
  const int b = off[node], e = off[node+1];
  float acc[8];
  #pragma unroll
  for (int k=0;k<8;k++) acc[k] = 0.f;

  if (useLds){
    int i = b;
    for (; i+16 <= e; i += 16){
      HU v[16];
      #pragma unroll
      for (int u=0;u<16;u++){
        int s = csrL[i - start + u];
        v[u].u = *(const uint4*)(slab + (size_t)s*32 + q8);
      }
      #pragma unroll
      for (int u=0;u<16;u++){
        #pragma unroll
        for (int k=0;k<8;k++) acc[k] += (float)v[u].h[k];
      }
    }
    for (; i+4 <= e; i += 4){
      HU v[4];
      #pragma unroll
      for (int u=0;u<4;u++){
        int s = csrL[i - start + u];
        v[u].u = *(const uint4*)(slab + (size_t)s*32 + q8);
      }
      #pragma unroll
      for (int u=0;u<4;u++){
        #pragma unroll
        for (int k=0;k<8;k++) acc[k] += (float)v[u].h[k];
      }
    }
    for (; i < e; i++){
      int s = csrL[i - start];
      HU v0; v0.u = *(const uint4*)(slab + (size_t)s*32 + q8);
      #pragma unroll
      for (int k=0;k<8;k++) acc[k] += (float)v0.h[k];
    }
  } else {
    // fallback: global csr reads (freak oversized window; never in practice)
    int i = b;
    for (; i+4 <= e; i += 4){
      HU v[4];
      #pragma unroll
      for (int u=0;u<4;u++){
        int s = csrS[i+u];
        v[u].u = *(const uint4*)(slab + (size_t)s*32 + q8);
      }
      #pragma unroll
      for (int u=0;u<4;u++){
        #pragma unroll
        for (int k=0;k<8;k++) acc[k] += (float)v[u].h[k];
      }
    }
    for (; i < e; i++){
      int s = csrS[i];
      HU v0; v0.u = *(const uint4*)(slab + (size_t)s*32 + q8);
      #pragma unroll
      for (int k=0;k<8;k++) acc[k] += (float)v0.h[k];
    }
  }

  float di = dinv[node];
  float d2 = di*di;
  HU os;
  #pragma unroll
  for (int k=0;k<8;k++) os.h[k] = (_Float16)(d2*acc[k]);
  __builtin_nontemporal_store(os.v, (u32x4*)(sOut + (size_t)slice*SSTR + (size_t)node*32 + q8));
}

// ---------------- fused layer GEMM via MFMA f16 — weights staged through LDS (r15, unchanged) ----------------

template<bool HEAD>
__global__ __launch_bounds__(256) void gemm_mfma_kernel(const ushort* s0,
    const ushort* __restrict__ s1, const ushort* __restrict__ s2, const ushort* __restrict__ s3,
    const ushort* __restrict__ Wt, const float* __restrict__ bias,
    const ushort* __restrict__ WtH, const float* __restrict__ biasH,
    const float* __restrict__ rdeg, const float* __restrict__ dinv,
    ushort* __restrict__ Ah, ushort* __restrict__ As, float* __restrict__ outF){
  __shared__ ushort Xs[64*136];
  __shared__ ushort Ws[128*136];
  const int tid  = threadIdx.x;
  const int wave = tid >> 6, lane = tid & 63;
  const int quad = lane >> 4, l16 = lane & 15;
  const int wm = wave & 1, wn = wave >> 1;
  const int row0 = blockIdx.x * 64;

  f32x4 acc[2][4];
  #pragma unroll
  for (int i=0;i<2;i++)
    #pragma unroll
    for (int j=0;j<4;j++) acc[i][j] = (f32x4){0.f,0.f,0.f,0.f};

  #pragma unroll
  for (int src=0; src<4; src++){
    const ushort* sp = (src==0)?s0:(src==1)?s1:(src==2)?s2:s3;
    const ushort* wsrc = Wt + (size_t)src*16384;
    __syncthreads();
    #pragma unroll
    for (int p=0;p<4;p++){
      int i = tid + p*256;
      int r = i >> 4, cc = i & 15;
      int gr = row0 + r;
      HU v; v.u = make_uint4(0u,0u,0u,0u);
      if (gr < N_NODES){
        if (src == 0){
          v.u = *(const uint4*)(sp + (size_t)gr*D + cc*8);
        } else {
          v.u = *(const uint4*)(sp + (size_t)(cc>>2)*SSTR + (size_t)gr*32 + (cc&3)*8);
          float rd = rdeg[gr];
          #pragma unroll
          for (int k=0;k<8;k++) v.h[k] = (_Float16)((float)v.h[k]*rd);
        }
      }
      *(uint4*)(&Xs[r*136 + cc*8]) = v.u;
    }
    #pragma unroll
    for (int p=0;p<8;p++){
      int i = tid + p*256;
      int n = i >> 4, cc = i & 15;
      *(uint4*)(&Ws[n*136 + cc*8]) = *(const uint4*)(wsrc + (size_t)n*D + cc*8);
    }
    __syncthreads();
    #pragma unroll
    for (int ks=0; ks<4; ks++){
      f16x8 a0 = *(const f16x8*)(&Xs[(wm*32 +      l16)*136 + ks*32 + quad*8]);
      f16x8 a1 = *(const f16x8*)(&Xs[(wm*32 + 16 + l16)*136 + ks*32 + quad*8]);
      #pragma unroll
      for (int j=0;j<4;j++){
        f16x8 bfrag = *(const f16x8*)(&Ws[(wn*64 + j*16 + l16)*136 + ks*32 + quad*8]);
        acc[0][j] = __builtin_amdgcn_mfma_f32_16x16x32_f16(a0, bfrag, acc[0][j], 0, 0, 0);
        acc[1][j] = __builtin_amdgcn_mfma_f32_16x16x32_f16(a1, bfrag, acc[1][j], 0, 0, 0);
      }
    }
  }

  __syncthreads();
  #pragma unroll
  for (int j=0;j<4;j++){
    int colj = wn*64 + j*16 + l16;
    float bv = bias[colj];
    #pragma unroll
    for (int i=0;i<2;i++){
      int lrow = wm*32 + i*16 + quad*4;
      #pragma unroll
      for (int r=0;r<4;r++){
        float v = fmaxf(acc[i][j][r] + bv, 0.f);
        Xs[(lrow + r)*136 + colj] = __builtin_bit_cast(ushort, (_Float16)v);
      }
    }
  }
  if (HEAD){
    #pragma unroll
    for (int p=0;p<8;p++){
      int i = tid + p*256;
      int n = i >> 4, cc = i & 15;
      *(uint4*)(&Ws[n*136 + cc*8]) = *(const uint4*)(WtH + (size_t)n*D + cc*8);
    }
  }
  __syncthreads();

  if (!HEAD){
    const int rbase = tid >> 4, cc = tid & 15;
    #pragma unroll
    for (int p=0;p<4;p++){
      int r = rbase + 16*p, gr = row0 + r;
      if (gr < N_NODES){
        HU h; h.u = *(const uint4*)(&Xs[r*136 + cc*8]);
        *(uint4*)(Ah + (size_t)gr*D + cc*8) = h.u;
        float di = dinv[gr];
        HU s;
        #pragma unroll
        for (int k=0;k<8;k++) s.h[k] = (_Float16)((float)h.h[k]*di);
        *(uint4*)(As + (size_t)(cc>>2)*SSTR + (size_t)gr*32 + (cc&3)*8) = s.u;
      }
    }
  } else {
    f32x4 acc2[2][4];
    #pragma unroll
    for (int i=0;i<2;i++)
      #pragma unroll
      for (int j=0;j<4;j++) acc2[i][j] = (f32x4){0.f,0.f,0.f,0.f};
    #pragma unroll
    for (int ks=0; ks<4; ks++){
      f16x8 a0 = *(const f16x8*)(&Xs[(wm*32 +      l16)*136 + ks*32 + quad*8]);
      f16x8 a1 = *(const f16x8*)(&Xs[(wm*32 + 16 + l16)*136 + ks*32 + quad*8]);
      #pragma unroll
      for (int j=0;j<4;j++){
        f16x8 bfrag = *(const f16x8*)(&Ws[(wn*64 + j*16 + l16)*136 + ks*32 + quad*8]);
        acc2[0][j] = __builtin_amdgcn_mfma_f32_16x16x32_f16(a0, bfrag, acc2[0][j], 0, 0, 0);
        acc2[1][j] = __builtin_amdgcn_mfma_f32_16x16x32_f16(a1, bfrag, acc2[1][j], 0, 0, 0);
      }
    }
    #pragma unroll
    for (int j=0;j<4;j++){
      int colj = wn*64 + j*16 + l16;
      float bv = biasH[colj];
      #pragma unroll
      for (int i=0;i<2;i++){
        int brow = row0 + wm*32 + i*16 + quad*4;
        #pragma unroll
        for (int r=0;r<4;r++){
          int grow = brow + r;
          if (grow < N_NODES)
            outF[(size_t)grow*D + colj] = acc2[i][j][r] + bv;
        }
      }
    }
  }
}

// ---------------- launch ----------------

extern "C" void kernel_launch(void* const* d_in, const int* in_sizes, int n_in,
                              void* d_out, int out_size, void* d_ws, size_t ws_size,
                              hipStream_t stream){
  const float* x  = (const float*)d_in[0];
  const int*   ei = (const int*)d_in[1];
  const float* W1 = (const float*)d_in[2];
  const float* b1 = (const float*)d_in[3];
  const float* W2 = (const float*)d_in[4];
  const float* b2 = (const float*)d_in[5];
  const float* W3 = (const float*)d_in[6];
  const float* b3 = (const float*)d_in[7];
  const float* Wf = (const float*)d_in[8];
  const float* bf = (const float*)d_in[9];
  float* out = (float*)d_out;

  const int* row = ei;            // edge_index[0]
  const int* col = ei + N_EDGES;  // edge_index[1]

  // workspace layout (~82 MB)
  char* w = (char*)d_ws;
  ushort* csrS = (ushort*)w;  w += (size_t)N_EDGES*2;
  ushort* x16  = (ushort*)w;  w += (size_t)N_NODES*D*2;
  ushort* xs16 = (ushort*)w;  w += (size_t)N_NODES*D*2;    // slab-major; reused as Ds after hop-1 (dead then)
  ushort* Ah   = (ushort*)w;  w += (size_t)N_NODES*D*2;    // row-major
  ushort* As   = (ushort*)w;  w += (size_t)N_NODES*D*2;    // slab-major
  ushort* Bs   = (ushort*)w;  w += (size_t)N_NODES*D*2;    // slab-major
  ushort* Cs   = (ushort*)w;  w += (size_t)N_NODES*D*2;    // slab-major
  ushort* Wt   = (ushort*)w;  w += (size_t)13*D*D*2;
  int* deg     = (int*)w;     w += (size_t)N_NODES*4;
  int* off     = (int*)w;     w += (size_t)(N_NODES+1)*4;
  int* chunkS  = (int*)w;     w += (size_t)256*4;
  float* dinv  = (float*)w;   w += (size_t)N_NODES*4;
  float* rdeg  = (float*)w;
  ushort* Ds = xs16;
  // Cc (16.8 MB = NSEG x NPAD ushort) aliases Ah+As: dead before gemm L1 writes Ah/As.
  ushort* Cc = Ah;

  const int GB  = (N_NODES + 63)/64;   // 782
  const int SBS = SNB*4;               // 3128 (4 XCD-pinned slices x 782 nodeblocks)

  histA_kernel<<<dim3(NODEBLKS,NSEG),1024,0,stream>>>(col, Cc);
  segprefix_kernel<<<NCHUNK,256,0,stream>>>(Cc, deg, dinv, rdeg, chunkS);
  scan3_kernel<<<NCHUNK,256,0,stream>>>(deg, chunkS, off);
  fillB_kernel<<<dim3(NODEBLKS,NSEG),1024,0,stream>>>(row, col, off, Cc, csrS);
  cvt_x_kernel<<<3125,256,0,stream>>>(x, dinv, x16, xs16);
  cvt_w_kernel<<<52,256,0,stream>>>(W1, W2, W3, Wf, Wt);

  // layer 1
  spmm_slab_kernel<<<SBS,256,0,stream>>>(xs16, Bs, off, csrS, dinv);
  spmm_slab_kernel<<<SBS,256,0,stream>>>(Bs,   Cs, off, csrS, dinv);
  spmm_slab_kernel<<<SBS,256,0,stream>>>(Cs,   Ds, off, csrS, dinv);
  gemm_mfma_kernel<false><<<GB,256,0,stream>>>(x16, Bs, Cs, Ds, Wt+0*16384, b1, nullptr, nullptr, rdeg, dinv, Ah, As, nullptr);
  // layer 2 (out aliases s0 = Ah; safe, see kernel comment)
  spmm_slab_kernel<<<SBS,256,0,stream>>>(As, Bs, off, csrS, dinv);
  spmm_slab_kernel<<<SBS,256,0,stream>>>(Bs, Cs, off, csrS, dinv);
  spmm_slab_kernel<<<SBS,256,0,stream>>>(Cs, Ds, off, csrS, dinv);
  gemm_mfma_kernel<false><<<GB,256,0,stream>>>(Ah, Bs, Cs, Ds, Wt+4*16384, b2, nullptr, nullptr, rdeg, dinv, Ah, As, nullptr);
  // layer 3 + fused head (fp32 out)
  spmm_slab_kernel<<<SBS,256,0,stream>>>(As, Bs, off, csrS, dinv);
  spmm_slab_kernel<<<SBS,256,0,stream>>>(Bs, Cs, off, csrS, dinv);
  spmm_slab_kernel<<<SBS,256,0,stream>>>(Cs, Ds, off, csrS, dinv);
  gemm_mfma_kernel<true ><<<GB,256,0,stream>>>(Ah, Bs, Cs, Ds, Wt+8*16384, b3, Wt+12*16384, bf, rdeg, dinv, nullptr, nullptr, out);
}